// Round 10
// baseline (291.886 us; speedup 1.0000x reference)
//
#include <hip/hip_runtime.h>
#include <hip/hip_bf16.h>
#include <hip/hip_fp16.h>

#define LEAKY 0.2f
#define NBMAX 1024     // max fine buckets (N <= 131072)
#define NCMAX 64       // max coarse buckets (N <= 131072)
#define CCH   4096     // edges per cscatter block
#define FCH   4096     // edges per fscatter chunk
#define NCHUNK 10      // fscatter chunks per coarse bucket (cap 40960 > max run ~34k)
#define SCAP2 3456     // bsort LDS capacity (avg 2048+896 pad, +10 sigma)

typedef _Float16 half8 __attribute__((ext_vector_type(8)));
typedef float f32x4 __attribute__((ext_vector_type(4)));

__device__ __forceinline__ float wave_sum64(float v) {
    #pragma unroll
    for (int m = 32; m > 0; m >>= 1) v += __shfl_xor(v, m, 64);
    return v;
}

// ---------------- W1 transpose+cvt ----------------
__launch_bounds__(256)
__global__ void w1cvt_kernel(const float* __restrict__ W, __half* __restrict__ Wt) {
    int i = blockIdx.x * 256 + threadIdx.x;
    int n = i >> 7, k = i & 127;
    Wt[i] = __float2half(W[k * 128 + n]);
}

// ---------------- GEMM1 (fp16 MFMA): feat1h = fp16(X @ W1), fused el1/er1 ----------------
// NOTE: kept BIT-IDENTICAL to the R7/R9-proven version (ffp-contract sensitivity).
__launch_bounds__(256)
__global__ void gemm1_kernel(const float* __restrict__ X, const __half* __restrict__ Wt,
                             const float* __restrict__ al1, const float* __restrict__ ar1,
                             __half* __restrict__ feat_h,
                             float* __restrict__ el1, float* __restrict__ er1, int N) {
    __shared__ __half Al[64 * 136];
    __shared__ __half Wl[128 * 136];
    const int tid = threadIdx.x;
    const int r0 = blockIdx.x * 64;
    {
        int n = tid >> 1, h0 = (tid & 1) * 64;
        const __half* gsrc = Wt + n * 128 + h0;
        __half* ldst = Wl + n * 136 + h0;
        #pragma unroll
        for (int i = 0; i < 8; i++)
            *(uint4*)(ldst + i * 8) = *(const uint4*)(gsrc + i * 8);
    }
    {
        int r = tid >> 2, c0 = (tid & 3) * 32;
        int rr = r0 + r;
        const float* gsrc = X + (size_t)rr * 128 + c0;
        __half* ldst = Al + r * 136 + c0;
        if (rr < N) {
            #pragma unroll
            for (int i = 0; i < 8; i++) {
                float4 v = *(const float4*)(gsrc + i * 4);
                __half2 a = __floats2half2_rn(v.x, v.y);
                __half2 b = __floats2half2_rn(v.z, v.w);
                uint2 pk; pk.x = *(unsigned*)&a; pk.y = *(unsigned*)&b;
                *(uint2*)(ldst + i * 4) = pk;
            }
        } else {
            uint2 z; z.x = 0; z.y = 0;
            #pragma unroll
            for (int i = 0; i < 8; i++) *(uint2*)(ldst + i * 4) = z;
        }
    }
    __syncthreads();
    const int wv = tid >> 6, lane = tid & 63;
    const int lm = lane & 15, lq = lane >> 4;
    f32x4 acc[8];
    #pragma unroll
    for (int t = 0; t < 8; t++) acc[t] = (f32x4){0.f, 0.f, 0.f, 0.f};
    const __half* arow = Al + (wv * 16 + lm) * 136 + lq * 8;
    const __half* brow = Wl + lm * 136 + lq * 8;
    #pragma unroll
    for (int ks = 0; ks < 4; ks++) {
        half8 af = *(const half8*)(arow + ks * 32);
        #pragma unroll
        for (int nt = 0; nt < 8; nt++) {
            half8 bf = *(const half8*)(brow + nt * 16 * 136 + ks * 32);
            acc[nt] = __builtin_amdgcn_mfma_f32_16x16x32_f16(af, bf, acc[nt], 0, 0, 0);
        }
    }
    __syncthreads();
    __half* Cl = Al;
    #pragma unroll
    for (int nt = 0; nt < 8; nt++) {
        #pragma unroll
        for (int r = 0; r < 4; r++) {
            int m = wv * 16 + lq * 4 + r;
            Cl[m * 136 + nt * 16 + lm] = __float2half(acc[nt][r]);
        }
    }
    __syncthreads();
    {
        int r = tid >> 2, c0 = (tid & 3) * 32;
        int rr = r0 + r;
        float pel = 0.f, per = 0.f;
        const __half* crow = Cl + r * 136 + c0;
        if (rr < N) {
            #pragma unroll
            for (int i = 0; i < 4; i++)
                *(uint4*)(feat_h + (size_t)rr * 128 + c0 + i * 8) = *(const uint4*)(crow + i * 8);
            #pragma unroll
            for (int c = 0; c < 32; c++) {
                float fv = __half2float(crow[c]);
                pel += fv * al1[c0 + c];
                per += fv * ar1[c0 + c];
            }
        }
        pel += __shfl_xor(pel, 1, 64);
        per += __shfl_xor(per, 1, 64);
        if ((tid & 1) == 0 && rr < N) {
            int h = (tid >> 1) & 1;
            el1[rr * 2 + h] = pel;
            er1[rr * 2 + h] = per;
        }
    }
}

// ---------------- fine-bucket histogram ----------------
__launch_bounds__(256)
__global__ void bhist_kernel(const int* __restrict__ dst, int* __restrict__ bcount,
                             int E, int NB) {
    __shared__ int hls[NBMAX];
    for (int i = threadIdx.x; i < NB; i += 256) hls[i] = 0;
    __syncthreads();
    int stride = gridDim.x * 256;
    for (int e = blockIdx.x * 256 + threadIdx.x; e < E; e += stride)
        atomicAdd(&hls[dst[e] >> 7], 1);
    __syncthreads();
    for (int i = threadIdx.x; i < NB; i += 256) {
        int c = hls[i];
        if (c) atomicAdd(&bcount[i], c);
    }
}

// ---------------- bucket scan (+ coarse cursor init) ----------------
__launch_bounds__(1024)
__global__ void bscan_kernel(const int* __restrict__ bcount, int* __restrict__ bstart,
                             int* __restrict__ bcursor, int* __restrict__ ccursor, int NB) {
    __shared__ int sd[NBMAX];
    int t = threadIdx.x;
    int v = (t < NB) ? bcount[t] : 0;
    sd[t] = v;
    __syncthreads();
    for (int o = 1; o < NBMAX; o <<= 1) {
        int x = (t >= o) ? sd[t - o] : 0;
        __syncthreads();
        sd[t] += x;
        __syncthreads();
    }
    if (t < NB) {
        int ex = sd[t] - v;
        bstart[t] = ex; bcursor[t] = ex;
        if ((t & 15) == 0) ccursor[t >> 4] = ex;   // coarse bucket start
    }
}

// ---------------- cscatter: coarse partition (2048-node buckets), coalesced flush ----------------
// record: {(src<<11)|(dst&2047) : u32, w : half2}
__launch_bounds__(256)
__global__ void cscatter_kernel(const int* __restrict__ src, const int* __restrict__ dst,
                                const float* __restrict__ el1, const float* __restrict__ er1,
                                int* __restrict__ ccursor, uint2* __restrict__ erec0, int E) {
    __shared__ uint2 stage[CCH];          // 32 KB
    __shared__ int h[NCMAX], hs[NCMAX + 1], cur[NCMAX], gb[NCMAX];
    const int tid = threadIdx.x;
    const int b0 = blockIdx.x * CCH;
    const int tcnt = min(CCH, E - b0);
    for (int i = tid; i < NCMAX; i += 256) h[i] = 0;
    __syncthreads();
    uint2 rec[16]; int cb[16];
    #pragma unroll
    for (int k = 0; k < 16; k++) {
        int e = b0 + k * 256 + tid;
        cb[k] = -1;
        if (e < E) {
            int s = src[e], d = dst[e];
            cb[k] = d >> 11;
            float2 lv = *((const float2*)el1 + s);
            float2 rv = *((const float2*)er1 + d);
            float e0 = lv.x + rv.x; e0 = (e0 > 0.f) ? e0 : LEAKY * e0;
            float e1 = lv.y + rv.y; e1 = (e1 > 0.f) ? e1 : LEAKY * e1;
            __half2 w = __floats2half2_rn(__expf(e0), __expf(e1));
            rec[k].x = ((unsigned)s << 11) | (unsigned)(d & 2047);
            rec[k].y = *(unsigned*)&w;
            atomicAdd(&h[cb[k]], 1);
        }
    }
    __syncthreads();
    int v = (tid < NCMAX) ? h[tid] : 0;
    if (tid < NCMAX) cur[tid] = v;
    __syncthreads();
    for (int o = 1; o < NCMAX; o <<= 1) {
        int x = 0;
        if (tid < NCMAX && tid >= o) x = cur[tid - o];
        __syncthreads();
        if (tid < NCMAX) cur[tid] += x;
        __syncthreads();
    }
    if (tid < NCMAX) hs[tid + 1] = cur[tid];
    if (tid == 0) hs[0] = 0;
    __syncthreads();
    if (tid < NCMAX) {
        cur[tid] = hs[tid];
        gb[tid] = (v > 0) ? atomicAdd(&ccursor[tid], v) : 0;
    }
    __syncthreads();
    #pragma unroll
    for (int k = 0; k < 16; k++) {
        if (cb[k] >= 0) {
            int p = atomicAdd(&cur[cb[k]], 1);
            stage[p] = rec[k];
        }
    }
    __syncthreads();
    for (int j = tid; j < tcnt; j += 256) {
        int lo = 0, hi = NCMAX;
        while (hi - lo > 1) { int mid = (lo + hi) >> 1; if (hs[mid] <= j) lo = mid; else hi = mid; }
        erec0[(size_t)gb[lo] + (j - hs[lo])] = stage[j];
    }
}

// ---------------- fscatter: fine partition within coarse runs, coalesced flush ----------------
__launch_bounds__(256)
__global__ void fscatter_kernel(const uint2* __restrict__ erec0, const int* __restrict__ bstart,
                                int* __restrict__ bcursor, uint2* __restrict__ erec,
                                int E, int NB) {
    __shared__ uint2 stage[FCH];          // 32 KB
    __shared__ int h[16], hs[17], cur[16], gb[16];
    const int c = blockIdx.x / NCHUNK;
    const int i = blockIdx.x % NCHUNK;
    const int cbeg = bstart[c << 4];
    const int nf16 = (c + 1) << 4;
    const int cend = (nf16 < NB) ? bstart[nf16] : E;
    const int beg = cbeg + i * FCH;
    if (beg >= cend) return;
    const int tcnt = min(FCH, cend - beg);
    const int tid = threadIdx.x;
    if (tid < 16) h[tid] = 0;
    __syncthreads();
    uint2 rec[16]; int fb[16];
    #pragma unroll
    for (int k = 0; k < 16; k++) {
        int j = k * 256 + tid;
        fb[k] = -1;
        if (j < tcnt) {
            uint2 r = erec0[(size_t)beg + j];
            rec[k] = r;
            fb[k] = (r.x >> 7) & 15;
            atomicAdd(&h[fb[k]], 1);
        }
    }
    __syncthreads();
    if (tid < 16) cur[tid] = h[tid];
    __syncthreads();
    for (int o = 1; o < 16; o <<= 1) {
        int x = 0;
        if (tid < 16 && tid >= o) x = cur[tid - o];
        __syncthreads();
        if (tid < 16) cur[tid] += x;
        __syncthreads();
    }
    if (tid < 16) hs[tid + 1] = cur[tid];
    if (tid == 0) hs[0] = 0;
    __syncthreads();
    if (tid < 16) {
        cur[tid] = hs[tid];
        int fi = (c << 4) + tid;
        gb[tid] = (h[tid] > 0 && fi < NB) ? atomicAdd(&bcursor[fi], h[tid]) : 0;
    }
    __syncthreads();
    #pragma unroll
    for (int k = 0; k < 16; k++) {
        if (fb[k] >= 0) {
            int p = atomicAdd(&cur[fb[k]], 1);
            stage[p] = rec[k];
        }
    }
    __syncthreads();
    for (int j = tid; j < tcnt; j += 256) {
        int lo = 0, hi = 16;
        while (hi - lo > 1) { int mid = (lo + hi) >> 1; if (hs[mid] <= j) lo = mid; else hi = mid; }
        erec[(size_t)gb[lo] + (j - hs[lo])] = stage[j];
    }
}

// ---------------- bsort: counting-sort fine run into padded per-node segments ----------------
__launch_bounds__(256)
__global__ void bsort_kernel(const uint2* __restrict__ erec,
                             const int* __restrict__ bstart, const int* __restrict__ bcount,
                             uint2* __restrict__ erec2,
                             int* __restrict__ rowstart, int* __restrict__ plen,
                             int* __restrict__ tlen,
                             int N, int NB) {
    __shared__ uint2 sorted[SCAP2];
    __shared__ int cnt[128], prs[129], curs[128];
    const int tid = threadIdx.x;
    const int b = blockIdx.x;
    const int node0 = b << 7;
    const int nd = min(128, N - node0);
    const int ebase = bstart[b];
    int ecnt = bcount[b];
    if (ecnt > SCAP2 - 896) ecnt = SCAP2 - 896;   // safety
    const int pbase = ebase + 896 * b;
    if (tid < 128) cnt[tid] = 0;
    __syncthreads();
    for (int j = tid; j < ecnt; j += 256)
        atomicAdd(&cnt[erec[ebase + j].x & 127], 1);
    __syncthreads();
    int pv = 0;
    if (tid < 128) { pv = (cnt[tid] + 7) & ~7; curs[tid] = pv; }
    __syncthreads();
    for (int o = 1; o < 128; o <<= 1) {
        int x = 0;
        if (tid < 128 && tid >= o) x = curs[tid - o];
        __syncthreads();
        if (tid < 128) curs[tid] += x;
        __syncthreads();
    }
    if (tid < 128) prs[tid + 1] = curs[tid];
    if (tid == 0) prs[0] = 0;
    __syncthreads();
    if (tid < 128) curs[tid] = prs[tid + 1] - pv;
    __syncthreads();
    const int pecnt = prs[128];
    for (int j = tid; j < pecnt; j += 256) { sorted[j].x = 0; sorted[j].y = 0; }
    __syncthreads();
    for (int j = tid; j < ecnt; j += 256) {
        uint2 r = erec[ebase + j];
        int p = atomicAdd(&curs[r.x & 127], 1);
        uint2 o2;
        o2.x = (r.x >> 11) << 8;   // src*256 = feat row byte offset
        o2.y = r.y;
        sorted[p] = o2;
    }
    __syncthreads();
    for (int j = tid; j < pecnt; j += 256) erec2[(size_t)pbase + j] = sorted[j];
    if (tid < nd) {
        rowstart[node0 + tid] = pbase + prs[tid];
        plen[node0 + tid] = prs[tid + 1] - prs[tid];
        tlen[node0 + tid] = cnt[tid];
    }
}

// ---------------- agg1 v3 (R7-proven, bit-identical): wave-per-node ----------------
__launch_bounds__(256)
__global__ void agg1_kernel(const char* __restrict__ fh, const uint2* __restrict__ erec2,
                            const float* __restrict__ b1, const float* __restrict__ W2,
                            const float* __restrict__ ar2,
                            const int* __restrict__ rowstart, const int* __restrict__ plen,
                            float* __restrict__ feat2, float* __restrict__ er2, int N) {
    int wid = (blockIdx.x * blockDim.x + threadIdx.x) >> 6;
    int lane = threadIdx.x & 63;
    if (wid >= N) return;
    const int len = plen[wid];
    const uint2* rp = erec2 + rowstart[wid];
    const int l5 = lane & 31;
    const int sub = lane >> 5;
    const unsigned hsh = (l5 < 16) ? 0u : 16u;
    float acc0 = 0.f, acc1 = 0.f, acc2 = 0.f, acc3 = 0.f, den = 0.f;
    for (int j = 0; j < len; j += 8) {
        uint2 r[4];
        #pragma unroll
        for (int u = 0; u < 4; u++) r[u] = rp[j + 2 * u + sub];
        uint2 v[4];
        #pragma unroll
        for (int u = 0; u < 4; u++)
            v[u] = *(const uint2*)(fh + (size_t)r[u].x + l5 * 8);
        #pragma unroll
        for (int u = 0; u < 4; u++) {
            float w = __half2float(__ushort_as_half((unsigned short)((r[u].y >> hsh) & 0xffffu)));
            den += w;
            float2 f0 = __half22float2(*(const __half2*)&v[u].x);
            float2 f1 = __half22float2(*(const __half2*)&v[u].y);
            acc0 += w * f0.x; acc1 += w * f0.y;
            acc2 += w * f1.x; acc3 += w * f1.y;
        }
    }
    acc0 += __shfl_xor(acc0, 32, 64);
    acc1 += __shfl_xor(acc1, 32, 64);
    acc2 += __shfl_xor(acc2, 32, 64);
    acc3 += __shfl_xor(acc3, 32, 64);
    den  += __shfl_xor(den,  32, 64);
    float inv = 1.f / fmaxf(den, 1e-30f);
    float4 bb = *(const float4*)(b1 + 4 * l5);
    float o0 = acc0 * inv + bb.x;
    float o1 = acc1 * inv + bb.y;
    float o2 = acc2 * inv + bb.z;
    float o3 = acc3 * inv + bb.w;
    float m0 = 0.5f * (o0 + __shfl_xor(o0, 16, 64));
    float m1 = 0.5f * (o1 + __shfl_xor(o1, 16, 64));
    float m2 = 0.5f * (o2 + __shfl_xor(o2, 16, 64));
    float m3 = 0.5f * (o3 + __shfl_xor(o3, 16, 64));
    m0 = fmaxf(m0, 0.f); m1 = fmaxf(m1, 0.f);
    m2 = fmaxf(m2, 0.f); m3 = fmaxf(m3, 0.f);
    const float* wrow = W2 + 8 * (l5 & 15);
    float4 wa = *(const float4*)wrow;
    float4 wb = *(const float4*)(wrow + 4);
    float p0 = m0 * wa.x + m1 * wa.z + m2 * wb.x + m3 * wb.z;
    float p1 = m0 * wa.y + m1 * wa.w + m2 * wb.y + m3 * wb.w;
    float c0 = 0.25f * wave_sum64(p0);
    float c1 = 0.25f * wave_sum64(p1);
    if (lane == 0) {
        float2 f2; f2.x = c0; f2.y = c1;
        *((float2*)feat2 + wid) = f2;
        er2[wid] = c0 * ar2[0] + c1 * ar2[1];
    }
}

// ---------------- agg2 v2: 16-lane group per node over sorted segments ----------------
__launch_bounds__(256)
__global__ void agg2_kernel(const float* __restrict__ feat2, const float* __restrict__ er2,
                            const float* __restrict__ al2, const float* __restrict__ b2,
                            const int* __restrict__ rowstart, const int* __restrict__ tlen,
                            const uint2* __restrict__ erec2, float* __restrict__ out, int N) {
    int node = (blockIdx.x * 256 + threadIdx.x) >> 4;
    int l4 = threadIdx.x & 15;
    if (node >= N) return;
    const int len = tlen[node];
    const uint2* rp = erec2 + rowstart[node];
    const float ern = er2[node];
    const float al20 = al2[0], al21 = al2[1];
    float den = 0.f, a0 = 0.f, a1 = 0.f;
    for (int j = l4; j < len; j += 16) {
        unsigned key = rp[j].x;                           // src*256
        float2 f = *((const float2*)feat2 + (key >> 8));
        float e = f.x * al20 + f.y * al21 + ern;
        e = (e > 0.f) ? e : LEAKY * e;
        float w = __expf(e);
        den += w;
        a0 += w * f.x;
        a1 += w * f.y;
    }
    #pragma unroll
    for (int m = 1; m < 16; m <<= 1) {
        den += __shfl_xor(den, m, 64);
        a0  += __shfl_xor(a0, m, 64);
        a1  += __shfl_xor(a1, m, 64);
    }
    if (l4 == 0) {
        float inv = 1.f / fmaxf(den, 1e-30f);
        float2 o;
        o.x = a0 * inv + b2[0];
        o.y = a1 * inv + b2[1];
        *((float2*)out + node) = o;
    }
}

extern "C" void kernel_launch(void* const* d_in, const int* in_sizes, int n_in,
                              void* d_out, int out_size, void* d_ws, size_t ws_size,
                              hipStream_t stream) {
    const float* in_feat = (const float*)d_in[0];
    const int*   src     = (const int*)d_in[1];
    const int*   dst     = (const int*)d_in[2];
    const float* W1      = (const float*)d_in[3];
    const float* al1     = (const float*)d_in[4];
    const float* ar1     = (const float*)d_in[5];
    const float* b1      = (const float*)d_in[6];
    const float* W2      = (const float*)d_in[7];
    const float* al2     = (const float*)d_in[8];
    const float* ar2     = (const float*)d_in[9];
    const float* b2      = (const float*)d_in[10];
    float* out = (float*)d_out;

    const int N = in_sizes[0] / 128;
    const int E = in_sizes[1];
    const int NB = (N + 127) >> 7;
    const int NC = (N + 2047) >> 11;

    // ---- workspace layout (16B-aligned chunks) ----
    char* ws = (char*)d_ws;
    __half* feat1h = (__half*)ws;                                // N*128 fp16
    size_t off = (size_t)N * 128 * 2;
    float* el1 = (float*)(ws + off); off += (size_t)N * 2 * 4;
    float* er1 = (float*)(ws + off); off += (size_t)N * 2 * 4;
    float* feat2 = (float*)(ws + off); off += (size_t)N * 2 * 4;
    float* er2 = (float*)(ws + off); off += (size_t)N * 4;
    int* bcount  = (int*)(ws + off); off += NBMAX * 4;           // zeroed
    int* bstart  = (int*)(ws + off); off += NBMAX * 4;
    int* bcursor = (int*)(ws + off); off += NBMAX * 4;
    int* ccursor = (int*)(ws + off); off += NCMAX * 4;
    int* rowstart = (int*)(ws + off); off += (size_t)N * 4;
    int* plen     = (int*)(ws + off); off += (size_t)N * 4;
    int* tlen     = (int*)(ws + off); off += (size_t)N * 4;
    uint2* erec0 = (uint2*)(ws + off); off += (size_t)E * 8;                  // coarse runs
    uint2* erec  = (uint2*)(ws + off); off += (size_t)E * 8;                  // fine runs
    uint2* erec2 = (uint2*)(ws + off); off += ((size_t)E + 896 * NB) * 8;    // sorted+padded
    __half* W1t = (__half*)(ws + off); off += 128 * 128 * 2;
    (void)ws_size; (void)n_in; (void)out_size;

    hipMemsetAsync(bcount, 0, NBMAX * 4, stream);

    w1cvt_kernel<<<64, 256, 0, stream>>>(W1, W1t);
    gemm1_kernel<<<(N + 63) / 64, 256, 0, stream>>>(in_feat, W1t, al1, ar1,
                                                    feat1h, el1, er1, N);

    const int nblkC = (E + CCH - 1) / CCH;
    bhist_kernel<<<nblkC, 256, 0, stream>>>(dst, bcount, E, NB);
    bscan_kernel<<<1, 1024, 0, stream>>>(bcount, bstart, bcursor, ccursor, NB);
    cscatter_kernel<<<nblkC, 256, 0, stream>>>(src, dst, el1, er1, ccursor, erec0, E);
    fscatter_kernel<<<NC * NCHUNK, 256, 0, stream>>>(erec0, bstart, bcursor, erec, E, NB);
    bsort_kernel<<<NB, 256, 0, stream>>>(erec, bstart, bcount, erec2, rowstart, plen, tlen, N, NB);

    agg1_kernel<<<(N * 64 + 255) / 256, 256, 0, stream>>>(
        (const char*)feat1h, erec2, b1, W2, ar2, rowstart, plen, feat2, er2, N);

    agg2_kernel<<<(N * 16 + 255) / 256, 256, 0, stream>>>(
        feat2, er2, al2, b2, rowstart, tlen, erec2, out, N);
}

// Round 12
// 280.108 us; speedup vs baseline: 1.0420x; 1.0420x over previous
//
#include <hip/hip_runtime.h>
#include <hip/hip_bf16.h>
#include <hip/hip_fp16.h>

#define LEAKY 0.2f
#define NBMAX 1024     // max fine buckets (N <= 131072)
#define CCH   4096     // edges per bscatter block
#define SCAP2 3456     // bsort LDS capacity (avg 2048+896 pad, +10 sigma)

typedef _Float16 half8 __attribute__((ext_vector_type(8)));
typedef float f32x4 __attribute__((ext_vector_type(4)));

__device__ __forceinline__ float wave_sum64(float v) {
    #pragma unroll
    for (int m = 32; m > 0; m >>= 1) v += __shfl_xor(v, m, 64);
    return v;
}

// nontemporal 8-byte load of a {u32,u32} record (builtin needs scalar int type)
__device__ __forceinline__ uint2 nt_load_rec(const uint2* p) {
    unsigned long long x = __builtin_nontemporal_load((const unsigned long long*)p);
    uint2 r;
    r.x = (unsigned)x;
    r.y = (unsigned)(x >> 32);
    return r;
}

// ---------------- W1 transpose+cvt ----------------
__launch_bounds__(256)
__global__ void w1cvt_kernel(const float* __restrict__ W, __half* __restrict__ Wt) {
    int i = blockIdx.x * 256 + threadIdx.x;
    int n = i >> 7, k = i & 127;
    Wt[i] = __float2half(W[k * 128 + n]);
}

// ---------------- GEMM1 (fp16 MFMA) + fused bucket histogram ----------------
// blocks [0, gemmBlocks): gemm (BIT-IDENTICAL math to R7/R9-proven version);
// blocks [gemmBlocks, ...): bucket histogram (independent work, runs concurrently)
__launch_bounds__(256)
__global__ void gemmhist_kernel(const float* __restrict__ X, const __half* __restrict__ Wt,
                                const float* __restrict__ al1, const float* __restrict__ ar1,
                                __half* __restrict__ feat_h,
                                float* __restrict__ el1, float* __restrict__ er1, int N,
                                const int* __restrict__ dst, int* __restrict__ bcount,
                                int E, int NB, int gemmBlocks) {
    __shared__ __half Al[64 * 136];
    __shared__ __half Wl[128 * 136];
    const int tid = threadIdx.x;
    if (blockIdx.x >= gemmBlocks) {
        // ---- histogram branch ----
        int* hls = (int*)Al;                       // reuse gemm LDS (4 KB needed)
        for (int i = tid; i < NB; i += 256) hls[i] = 0;
        __syncthreads();
        int hb = blockIdx.x - gemmBlocks;
        int stride = (gridDim.x - gemmBlocks) * 256;
        for (int e = hb * 256 + tid; e < E; e += stride)
            atomicAdd(&hls[dst[e] >> 7], 1);
        __syncthreads();
        for (int i = tid; i < NB; i += 256) {
            int c = hls[i];
            if (c) atomicAdd(&bcount[i], c);
        }
        return;
    }
    const int r0 = blockIdx.x * 64;
    {
        int n = tid >> 1, h0 = (tid & 1) * 64;
        const __half* gsrc = Wt + n * 128 + h0;
        __half* ldst = Wl + n * 136 + h0;
        #pragma unroll
        for (int i = 0; i < 8; i++)
            *(uint4*)(ldst + i * 8) = *(const uint4*)(gsrc + i * 8);
    }
    {
        int r = tid >> 2, c0 = (tid & 3) * 32;
        int rr = r0 + r;
        const float* gsrc = X + (size_t)rr * 128 + c0;
        __half* ldst = Al + r * 136 + c0;
        if (rr < N) {
            #pragma unroll
            for (int i = 0; i < 8; i++) {
                float4 v = *(const float4*)(gsrc + i * 4);
                __half2 a = __floats2half2_rn(v.x, v.y);
                __half2 b = __floats2half2_rn(v.z, v.w);
                uint2 pk; pk.x = *(unsigned*)&a; pk.y = *(unsigned*)&b;
                *(uint2*)(ldst + i * 4) = pk;
            }
        } else {
            uint2 z; z.x = 0; z.y = 0;
            #pragma unroll
            for (int i = 0; i < 8; i++) *(uint2*)(ldst + i * 4) = z;
        }
    }
    __syncthreads();
    const int wv = tid >> 6, lane = tid & 63;
    const int lm = lane & 15, lq = lane >> 4;
    f32x4 acc[8];
    #pragma unroll
    for (int t = 0; t < 8; t++) acc[t] = (f32x4){0.f, 0.f, 0.f, 0.f};
    const __half* arow = Al + (wv * 16 + lm) * 136 + lq * 8;
    const __half* brow = Wl + lm * 136 + lq * 8;
    #pragma unroll
    for (int ks = 0; ks < 4; ks++) {
        half8 af = *(const half8*)(arow + ks * 32);
        #pragma unroll
        for (int nt = 0; nt < 8; nt++) {
            half8 bf = *(const half8*)(brow + nt * 16 * 136 + ks * 32);
            acc[nt] = __builtin_amdgcn_mfma_f32_16x16x32_f16(af, bf, acc[nt], 0, 0, 0);
        }
    }
    __syncthreads();
    __half* Cl = Al;
    #pragma unroll
    for (int nt = 0; nt < 8; nt++) {
        #pragma unroll
        for (int r = 0; r < 4; r++) {
            int m = wv * 16 + lq * 4 + r;
            Cl[m * 136 + nt * 16 + lm] = __float2half(acc[nt][r]);
        }
    }
    __syncthreads();
    {
        int r = tid >> 2, c0 = (tid & 3) * 32;
        int rr = r0 + r;
        float pel = 0.f, per = 0.f;
        const __half* crow = Cl + r * 136 + c0;
        if (rr < N) {
            #pragma unroll
            for (int i = 0; i < 4; i++)
                *(uint4*)(feat_h + (size_t)rr * 128 + c0 + i * 8) = *(const uint4*)(crow + i * 8);
            #pragma unroll
            for (int c = 0; c < 32; c++) {
                float fv = __half2float(crow[c]);
                pel += fv * al1[c0 + c];
                per += fv * ar1[c0 + c];
            }
        }
        pel += __shfl_xor(pel, 1, 64);
        per += __shfl_xor(per, 1, 64);
        if ((tid & 1) == 0 && rr < N) {
            int h = (tid >> 1) & 1;
            el1[rr * 2 + h] = pel;
            er1[rr * 2 + h] = per;
        }
    }
}

// ---------------- bucket scan ----------------
__launch_bounds__(1024)
__global__ void bscan_kernel(const int* __restrict__ bcount, int* __restrict__ bstart,
                             int* __restrict__ bcursor, int NB) {
    __shared__ int sd[NBMAX];
    int t = threadIdx.x;
    int v = (t < NB) ? bcount[t] : 0;
    sd[t] = v;
    __syncthreads();
    for (int o = 1; o < NBMAX; o <<= 1) {
        int x = (t >= o) ? sd[t - o] : 0;
        __syncthreads();
        sd[t] += x;
        __syncthreads();
    }
    if (t < NB) { int ex = sd[t] - v; bstart[t] = ex; bcursor[t] = ex; }
}

// ---------------- bucket scatter: erec = {(src<<7)|dl : u32, w : half2} ----------------
__launch_bounds__(256)
__global__ void bscatter_kernel(const int* __restrict__ src, const int* __restrict__ dst,
                                const float* __restrict__ el1, const float* __restrict__ er1,
                                int* __restrict__ bcursor, uint2* __restrict__ erec,
                                int E, int NB) {
    __shared__ int hls[NBMAX];
    for (int i = threadIdx.x; i < NB; i += 256) hls[i] = 0;
    __syncthreads();
    const int b0 = blockIdx.x * CCH;
    uint2 ureg[16];
    int breg[16];
    #pragma unroll
    for (int k = 0; k < 16; k++) {
        int e = b0 + k * 256 + threadIdx.x;
        if (e < E) {
            int s = src[e], d = dst[e];
            int bk = d >> 7;
            breg[k] = bk;
            float2 lv = *((const float2*)el1 + s);
            float2 rv = *((const float2*)er1 + d);
            float e0 = lv.x + rv.x; e0 = (e0 > 0.f) ? e0 : LEAKY * e0;
            float e1 = lv.y + rv.y; e1 = (e1 > 0.f) ? e1 : LEAKY * e1;
            __half2 w = __floats2half2_rn(__expf(e0), __expf(e1));
            ureg[k].x = ((unsigned)s << 7) | (unsigned)(d & 127);
            ureg[k].y = *(unsigned*)&w;
            atomicAdd(&hls[bk], 1);
        } else breg[k] = -1;
    }
    __syncthreads();
    for (int b = threadIdx.x; b < NB; b += 256) {
        int c = hls[b];
        if (c) hls[b] = atomicAdd(&bcursor[b], c);   // hls becomes global cursor
    }
    __syncthreads();
    #pragma unroll
    for (int k = 0; k < 16; k++) {
        if (breg[k] >= 0) {
            int p = atomicAdd(&hls[breg[k]], 1);
            erec[p] = ureg[k];
        }
    }
}

// ---------------- bsort: counting-sort bucket run into padded per-node segments ----------------
__launch_bounds__(256)
__global__ void bsort_kernel(const uint2* __restrict__ erec,
                             const int* __restrict__ bstart, const int* __restrict__ bcount,
                             uint2* __restrict__ erec2,
                             int* __restrict__ rowstart, int* __restrict__ plen,
                             int* __restrict__ tlen,
                             int N, int NB) {
    __shared__ uint2 sorted[SCAP2];
    __shared__ int cnt[128], prs[129], curs[128];
    const int tid = threadIdx.x;
    const int b = blockIdx.x;
    const int node0 = b << 7;
    const int nd = min(128, N - node0);
    const int ebase = bstart[b];
    int ecnt = bcount[b];
    if (ecnt > SCAP2 - 896) ecnt = SCAP2 - 896;   // safety
    const int pbase = ebase + 896 * b;
    if (tid < 128) cnt[tid] = 0;
    __syncthreads();
    for (int j = tid; j < ecnt; j += 256)
        atomicAdd(&cnt[erec[ebase + j].x & 127], 1);
    __syncthreads();
    int pv = 0;
    if (tid < 128) { pv = (cnt[tid] + 7) & ~7; curs[tid] = pv; }
    __syncthreads();
    for (int o = 1; o < 128; o <<= 1) {
        int x = 0;
        if (tid < 128 && tid >= o) x = curs[tid - o];
        __syncthreads();
        if (tid < 128) curs[tid] += x;
        __syncthreads();
    }
    if (tid < 128) prs[tid + 1] = curs[tid];
    if (tid == 0) prs[0] = 0;
    __syncthreads();
    if (tid < 128) curs[tid] = prs[tid + 1] - pv;
    __syncthreads();
    const int pecnt = prs[128];
    for (int j = tid; j < pecnt; j += 256) { sorted[j].x = 0; sorted[j].y = 0; }
    __syncthreads();
    for (int j = tid; j < ecnt; j += 256) {
        uint2 r = erec[ebase + j];
        int p = atomicAdd(&curs[r.x & 127], 1);
        uint2 o2;
        o2.x = (r.x >> 7) << 8;   // src*256 = feat row byte offset
        o2.y = r.y;
        sorted[p] = o2;
    }
    __syncthreads();
    for (int j = tid; j < pecnt; j += 256) erec2[(size_t)pbase + j] = sorted[j];
    if (tid < nd) {
        rowstart[node0 + tid] = pbase + prs[tid];
        plen[node0 + tid] = prs[tid + 1] - prs[tid];
        tlen[node0 + tid] = cnt[tid];
    }
}

// ---------------- agg1 v3u: wave-per-node, unroll x2 (bit-identical fp order), nt record loads ----------------
__launch_bounds__(256)
__global__ void agg1_kernel(const char* __restrict__ fh, const uint2* __restrict__ erec2,
                            const float* __restrict__ b1, const float* __restrict__ W2,
                            const float* __restrict__ ar2,
                            const int* __restrict__ rowstart, const int* __restrict__ plen,
                            float* __restrict__ feat2, float* __restrict__ er2, int N) {
    int wid = (blockIdx.x * blockDim.x + threadIdx.x) >> 6;
    int lane = threadIdx.x & 63;
    if (wid >= N) return;
    const int len = plen[wid];
    const uint2* rp = erec2 + rowstart[wid];
    const int l5 = lane & 31;
    const int sub = lane >> 5;
    const unsigned hsh = (l5 < 16) ? 0u : 16u;
    float acc0 = 0.f, acc1 = 0.f, acc2 = 0.f, acc3 = 0.f, den = 0.f;
    int j = 0;
    for (; j + 16 <= len; j += 16) {
        uint2 r[8];
        #pragma unroll
        for (int u = 0; u < 4; u++) r[u] = nt_load_rec(rp + j + 2 * u + sub);
        #pragma unroll
        for (int u = 0; u < 4; u++) r[4 + u] = nt_load_rec(rp + j + 8 + 2 * u + sub);
        uint2 v[8];
        #pragma unroll
        for (int u = 0; u < 8; u++)
            v[u] = *(const uint2*)(fh + (size_t)r[u].x + l5 * 8);
        #pragma unroll
        for (int u = 0; u < 8; u++) {
            float w = __half2float(__ushort_as_half((unsigned short)((r[u].y >> hsh) & 0xffffu)));
            den += w;
            float2 f0 = __half22float2(*(const __half2*)&v[u].x);
            float2 f1 = __half22float2(*(const __half2*)&v[u].y);
            acc0 += w * f0.x; acc1 += w * f0.y;
            acc2 += w * f1.x; acc3 += w * f1.y;
        }
    }
    if (j < len) {
        uint2 r[4];
        #pragma unroll
        for (int u = 0; u < 4; u++) r[u] = nt_load_rec(rp + j + 2 * u + sub);
        uint2 v[4];
        #pragma unroll
        for (int u = 0; u < 4; u++)
            v[u] = *(const uint2*)(fh + (size_t)r[u].x + l5 * 8);
        #pragma unroll
        for (int u = 0; u < 4; u++) {
            float w = __half2float(__ushort_as_half((unsigned short)((r[u].y >> hsh) & 0xffffu)));
            den += w;
            float2 f0 = __half22float2(*(const __half2*)&v[u].x);
            float2 f1 = __half22float2(*(const __half2*)&v[u].y);
            acc0 += w * f0.x; acc1 += w * f0.y;
            acc2 += w * f1.x; acc3 += w * f1.y;
        }
    }
    acc0 += __shfl_xor(acc0, 32, 64);
    acc1 += __shfl_xor(acc1, 32, 64);
    acc2 += __shfl_xor(acc2, 32, 64);
    acc3 += __shfl_xor(acc3, 32, 64);
    den  += __shfl_xor(den,  32, 64);
    float inv = 1.f / fmaxf(den, 1e-30f);
    float4 bb = *(const float4*)(b1 + 4 * l5);
    float o0 = acc0 * inv + bb.x;
    float o1 = acc1 * inv + bb.y;
    float o2 = acc2 * inv + bb.z;
    float o3 = acc3 * inv + bb.w;
    float m0 = 0.5f * (o0 + __shfl_xor(o0, 16, 64));
    float m1 = 0.5f * (o1 + __shfl_xor(o1, 16, 64));
    float m2 = 0.5f * (o2 + __shfl_xor(o2, 16, 64));
    float m3 = 0.5f * (o3 + __shfl_xor(o3, 16, 64));
    m0 = fmaxf(m0, 0.f); m1 = fmaxf(m1, 0.f);
    m2 = fmaxf(m2, 0.f); m3 = fmaxf(m3, 0.f);
    const float* wrow = W2 + 8 * (l5 & 15);
    float4 wa = *(const float4*)wrow;
    float4 wb = *(const float4*)(wrow + 4);
    float p0 = m0 * wa.x + m1 * wa.z + m2 * wb.x + m3 * wb.z;
    float p1 = m0 * wa.y + m1 * wa.w + m2 * wb.y + m3 * wb.w;
    float c0 = 0.25f * wave_sum64(p0);
    float c1 = 0.25f * wave_sum64(p1);
    if (lane == 0) {
        float2 f2; f2.x = c0; f2.y = c1;
        *((float2*)feat2 + wid) = f2;
        er2[wid] = c0 * ar2[0] + c1 * ar2[1];
    }
}

// ---------------- agg2 v2: 16-lane group per node over sorted segments ----------------
__launch_bounds__(256)
__global__ void agg2_kernel(const float* __restrict__ feat2, const float* __restrict__ er2,
                            const float* __restrict__ al2, const float* __restrict__ b2,
                            const int* __restrict__ rowstart, const int* __restrict__ tlen,
                            const uint2* __restrict__ erec2, float* __restrict__ out, int N) {
    int node = (blockIdx.x * 256 + threadIdx.x) >> 4;
    int l4 = threadIdx.x & 15;
    if (node >= N) return;
    const int len = tlen[node];
    const uint2* rp = erec2 + rowstart[node];
    const float ern = er2[node];
    const float al20 = al2[0], al21 = al2[1];
    float den = 0.f, a0 = 0.f, a1 = 0.f;
    for (int j = l4; j < len; j += 16) {
        uint2 rec = nt_load_rec(rp + j);
        unsigned key = rec.x;                             // src*256
        float2 f = *((const float2*)feat2 + (key >> 8));
        float e = f.x * al20 + f.y * al21 + ern;
        e = (e > 0.f) ? e : LEAKY * e;
        float w = __expf(e);
        den += w;
        a0 += w * f.x;
        a1 += w * f.y;
    }
    #pragma unroll
    for (int m = 1; m < 16; m <<= 1) {
        den += __shfl_xor(den, m, 64);
        a0  += __shfl_xor(a0, m, 64);
        a1  += __shfl_xor(a1, m, 64);
    }
    if (l4 == 0) {
        float inv = 1.f / fmaxf(den, 1e-30f);
        float2 o;
        o.x = a0 * inv + b2[0];
        o.y = a1 * inv + b2[1];
        *((float2*)out + node) = o;
    }
}

extern "C" void kernel_launch(void* const* d_in, const int* in_sizes, int n_in,
                              void* d_out, int out_size, void* d_ws, size_t ws_size,
                              hipStream_t stream) {
    const float* in_feat = (const float*)d_in[0];
    const int*   src     = (const int*)d_in[1];
    const int*   dst     = (const int*)d_in[2];
    const float* W1      = (const float*)d_in[3];
    const float* al1     = (const float*)d_in[4];
    const float* ar1     = (const float*)d_in[5];
    const float* b1      = (const float*)d_in[6];
    const float* W2      = (const float*)d_in[7];
    const float* al2     = (const float*)d_in[8];
    const float* ar2     = (const float*)d_in[9];
    const float* b2      = (const float*)d_in[10];
    float* out = (float*)d_out;

    const int N = in_sizes[0] / 128;
    const int E = in_sizes[1];
    const int NB = (N + 127) >> 7;

    // ---- workspace layout (16B-aligned chunks) ----
    char* ws = (char*)d_ws;
    __half* feat1h = (__half*)ws;                                // N*128 fp16
    size_t off = (size_t)N * 128 * 2;
    float* el1 = (float*)(ws + off); off += (size_t)N * 2 * 4;
    float* er1 = (float*)(ws + off); off += (size_t)N * 2 * 4;
    float* feat2 = (float*)(ws + off); off += (size_t)N * 2 * 4;
    float* er2 = (float*)(ws + off); off += (size_t)N * 4;
    int* bcount  = (int*)(ws + off); off += NBMAX * 4;           // zeroed
    int* bstart  = (int*)(ws + off); off += NBMAX * 4;
    int* bcursor = (int*)(ws + off); off += NBMAX * 4;
    int* rowstart = (int*)(ws + off); off += (size_t)N * 4;
    int* plen     = (int*)(ws + off); off += (size_t)N * 4;
    int* tlen     = (int*)(ws + off); off += (size_t)N * 4;
    uint2* erec  = (uint2*)(ws + off); off += (size_t)E * 8;                  // bucket runs
    uint2* erec2 = (uint2*)(ws + off); off += ((size_t)E + 896 * NB) * 8;    // sorted+padded
    __half* W1t = (__half*)(ws + off); off += 128 * 128 * 2;
    (void)ws_size; (void)n_in; (void)out_size;

    hipMemsetAsync(bcount, 0, NBMAX * 4, stream);

    w1cvt_kernel<<<64, 256, 0, stream>>>(W1, W1t);

    const int gemmBlocks = (N + 63) / 64;
    const int nblkC = (E + CCH - 1) / CCH;
    gemmhist_kernel<<<gemmBlocks + nblkC, 256, 0, stream>>>(
        in_feat, W1t, al1, ar1, feat1h, el1, er1, N,
        dst, bcount, E, NB, gemmBlocks);

    bscan_kernel<<<1, 1024, 0, stream>>>(bcount, bstart, bcursor, NB);
    bscatter_kernel<<<nblkC, 256, 0, stream>>>(src, dst, el1, er1, bcursor, erec, E, NB);
    bsort_kernel<<<NB, 256, 0, stream>>>(erec, bstart, bcount, erec2, rowstart, plen, tlen, N, NB);

    agg1_kernel<<<(N * 64 + 255) / 256, 256, 0, stream>>>(
        (const char*)feat1h, erec2, b1, W2, ar2, rowstart, plen, feat2, er2, N);

    agg2_kernel<<<(N * 16 + 255) / 256, 256, 0, stream>>>(
        feat2, er2, al2, b2, rowstart, tlen, erec2, out, N);
}